// Round 15
// baseline (279.609 us; speedup 1.0000x reference)
//
#include <hip/hip_runtime.h>
#include <hip/hip_bf16.h>
#include <math.h>

#define NN 2048           // x is 2048 x 2048 (DP grid = [0,2046]^2)
#define TROWS 1040        // table rows per half (1024 + prefetch margin)
#define NW 8              // 8 waves per WG (2 per SIMD), CPL=4
#define RPS 32            // rows per wave per step (32-row cadence: ~57 nats << 88)
#define LN2 0.6931471805599453

static __device__ __forceinline__ float2 f2max(float2 a, float2 b) {
  return make_float2(fmaxf(a.x, b.x), fmaxf(a.y, b.y));
}

// d_ws layout (floats): tab[TROWS][NN] | tabR[TROWS][NN] | arr: S,tg,yc,gM,gY (5*NN) | res (4 words)

__global__ void prep_kernel(const float* __restrict__ x, float* __restrict__ tab,
                            float* __restrict__ tabR) {
  const int c = blockIdx.x * 256 + threadIdx.x;
  const int t = blockIdx.y;
  tab[(size_t)t * NN + c] = __expf(x[(size_t)t * NN + c]);
  const int rr = 2048 - t, cc = 2048 - c;
  float v = 0.f;
  if (rr < 2048 && cc < 2048) v = __expf(x[(size_t)rr * NN + cc]);
  tabR[(size_t)t * NN + c] = v;
}

// ---------------------------------------------------------------------------
// R15 = R14's proven schedule with the columnwise math in float2 pairs so the
// compiler can emit v_pk_{fma,mul,add,max}_f32 (dual f32/instr). Only the Q
// Horner and the X gap-chain stay scalar (serial deps). Named float2 carries
// -- no register arrays (rule #20). All sync/exponent machinery identical.
// ---------------------------------------------------------------------------
template<int MODE>
__global__ __launch_bounds__(NW * 64)
void sw2_kernel(const float* __restrict__ x, const float* __restrict__ tab,
                const float* __restrict__ tabR, float* __restrict__ arr,
                float* __restrict__ out) {
  const int tid  = threadIdx.x;
  const int lane = tid & 63;
  const int wv   = __builtin_amdgcn_readfirstlane(tid >> 6);   // 0..7
  const int c0   = (wv << 8) + lane * 4;

  __shared__ float2 E[2][NW + 1][RPS];   // [parity][wave+1][row]; wave-0 input = zeros
  __shared__ float  red[2][NW];
  __shared__ float  wsum[NW];

  for (int i = tid; i < 2 * (NW + 1) * RPS; i += NW * 64)
    ((float2*)E)[i] = make_float2(0.f, 0.f);
  __syncthreads();

  const float cGO = 0.006737946999085467f;   // e^-5
  const float cGE = 0.36787944117144233f;    // e^-1
  const float C4  = 0.01831563888873418f;    // e^-4
  const float2 cGO2 = make_float2(cGO, cGO);
  const float2 cGE2 = make_float2(cGE, cGE);
  const bool isL0 = (lane == 0), isL1 = (lane == 1), isL63 = (lane == 63);

  if (MODE == 0 || blockIdx.x == 0) {
    // ======================= FORWARD =======================
    const int SPW   = ((MODE == 0) ? 2048 : 1024) / RPS;
    const int NSTEP = SPW + NW - 1;
    float2 s1a = make_float2(0.f, 0.f), s1b = make_float2(0.f, 0.f);
    float2 tga = make_float2(0.f, 0.f), tgb = make_float2(0.f, 0.f);
    float2 yca = make_float2(0.f, 0.f), ycb = make_float2(0.f, 0.f);
    float2 acc2 = make_float2(0.f, 0.f), one2 = make_float2(1.f, 1.f);
    float2 tmx2 = make_float2(0.f, 0.f);
    float escale = 1.f, SinC = 0.f;
    int Etot = 0;
    const float* src = ((MODE == 0) ? x : tab) + c0;
    float4 pfA = *(const float4*)(src);
    float4 pfB = *(const float4*)(src + NN);
    float4 pfC = *(const float4*)(src + 2 * NN);
    float4 pfD = *(const float4*)(src + 3 * NN);
    const float* pl = src + 4 * NN;
    int rown = 4;

    int cr_ = 0, pr_ = 0;
    float prevEdx = 0.f;
    auto rowF = [&](float4 ev, int k, bool first) {
      float2 e01 = make_float2(ev.x, ev.y);
      float2 e23 = make_float2(ev.z, ev.w);
      if (MODE == 0) {
        e01.x = __expf(e01.x); e01.y = __expf(e01.y);
        e23.x = __expf(e23.x); e23.y = __expf(e23.y);
      }
      const float2 edc = E[cr_][wv][k];
      const float Sr = first ? SinC : prevEdx * escale;
      const float Xi = edc.y * escale;
      prevEdx = edc.x;

      float sh  = __shfl_up(s1b.y, 1);
      float sd0 = isL0 ? Sr : sh;
      float2 d01 = make_float2(sd0,   s1a.x);
      float2 d23 = make_float2(s1a.y, s1b.x);
      acc2 = e01 * d01 + acc2;
      acc2 = e23 * d23 + acc2;
      float2 M01 = e01 * (d01 + one2);
      float2 M23 = e23 * (d23 + one2);

      float Q  = fmaf(cGE, fmaf(cGE, fmaf(cGE, M01.x, M01.y), M23.x), M23.y);
      float q1 = __shfl_up(Q, 1);
      float q2 = __shfl_up(Q, 2);
      q2 = isL1 ? Xi : q2;
      float X0 = fmaf(C4, q2, q1);
      X0 = isL0 ? Xi : X0;
      float X1 = fmaf(cGE, X0, M01.x);
      float X2 = fmaf(cGE, X1, M01.y);
      float X3 = fmaf(cGE, X2, M23.x);
      float2 X01 = make_float2(X0, X1);
      float2 X23 = make_float2(X2, X3);

      float2 T01 = cGO2 * X01 + M01;
      float2 T23 = cGO2 * X23 + M23;
      float2 Y01 = cGE2 * yca + tga;
      float2 Y23 = cGE2 * ycb + tgb;
      float2 S01 = T01 + Y01;
      float2 S23 = T23 + Y23;
      tmx2 = f2max(tmx2, f2max(S01, S23));
      tga = cGO2 * T01; tgb = cGO2 * T23;
      yca = Y01; ycb = Y23; s1a = S01; s1b = S23;

      if (isL63) E[pr_][wv + 1][k] = make_float2(S23.y, fmaf(C4, X0, Q));
    };

    for (int s = 0; s < NSTEP; ++s) {
      pr_ = s & 1; cr_ = pr_ ^ 1;
      const bool act = (s >= wv) && (s < wv + SPW);
      if (act) {
        prevEdx = 0.f;
        for (int kk = 0; kk < RPS / 4; ++kk) {
          const int kb = kk << 2;
          float4 e0 = pfA, e1 = pfB, e2 = pfC, e3 = pfD;
          if (MODE == 1) {
            pfA = *(const float4*)pl;          pl += NN;
            pfB = *(const float4*)pl;          pl += NN;
            pfC = *(const float4*)pl;          pl += NN;
            pfD = *(const float4*)pl;          pl += NN;
          } else {
            int r0 = (rown     < NN) ? rown     : NN - 1;
            int r1 = (rown + 1 < NN) ? rown + 1 : NN - 1;
            int r2 = (rown + 2 < NN) ? rown + 2 : NN - 1;
            int r3 = (rown + 3 < NN) ? rown + 3 : NN - 1;
            pfA = *(const float4*)(src + (size_t)r0 * NN);
            pfB = *(const float4*)(src + (size_t)r1 * NN);
            pfC = *(const float4*)(src + (size_t)r2 * NN);
            pfD = *(const float4*)(src + (size_t)r3 * NN);
            rown += 4;
          }
          rowF(e0, kb + 0, kk == 0);
          rowF(e1, kb + 1, false);
          rowF(e2, kb + 2, false);
          rowF(e3, kb + 3, false);
        }
        SinC = prevEdx * escale;
      }
      { // per-step shared-exponent rescale (32 rows)
        float m = fmaxf(tmx2.x, tmx2.y);
        m = fmaxf(m, __shfl_xor(m, 1));  m = fmaxf(m, __shfl_xor(m, 2));
        m = fmaxf(m, __shfl_xor(m, 4));  m = fmaxf(m, __shfl_xor(m, 8));
        m = fmaxf(m, __shfl_xor(m, 16)); m = fmaxf(m, __shfl_xor(m, 32));
        if (lane == 0) red[pr_][wv] = m;
      }
      __syncthreads();
      {
        float mm = red[pr_][lane & (NW - 1)];
        mm = fmaxf(mm, __shfl_xor(mm, 1));
        mm = fmaxf(mm, __shfl_xor(mm, 2));
        mm = fmaxf(mm, __shfl_xor(mm, 4));
        tmx2 = make_float2(0.f, 0.f); escale = 1.f;
        int e = (mm > 0.f) ? ilogbf(mm) : 0;
        if (e > 126) e = 126; if (e < -126) e = -126;
        if (e != 0) {
          const float c = ldexpf(1.f, -e);
          const float2 c2 = make_float2(c, c);
          s1a = s1a * c2; s1b = s1b * c2;
          tga = tga * c2; tgb = tgb * c2;
          yca = yca * c2; ycb = ycb * c2;
          acc2 = acc2 * c2; one2 = one2 * c2; SinC *= c;
          escale = c; Etot += e;
        }
      }
    }
    float ssum = acc2.x + acc2.y;
    ssum += __shfl_xor(ssum, 1);  ssum += __shfl_xor(ssum, 2);
    ssum += __shfl_xor(ssum, 4);  ssum += __shfl_xor(ssum, 8);
    ssum += __shfl_xor(ssum, 16); ssum += __shfl_xor(ssum, 32);
    if (lane == 0) wsum[wv] = ssum;
    __syncthreads();
    if (MODE == 0) {
      if (tid == 0) {
        double tot = 0.0;
        #pragma unroll
        for (int k = 0; k < NW; ++k) tot += (double)wsum[k];
        out[0] = (float)(log(tot) + (double)Etot * LN2);
      }
    } else {
      *(float4*)(arr + c0)          = make_float4(s1a.x, s1a.y, s1b.x, s1b.y);  // S[1023,b]
      *(float4*)(arr + NN + c0)     = make_float4(tga.x, tga.y, tgb.x, tgb.y);  // cGO*T
      *(float4*)(arr + 2 * NN + c0) = make_float4(yca.x, yca.y, ycb.x, ycb.y);  // Y
      if (tid == 0) {
        float t = 0.f;
        #pragma unroll
        for (int k = 0; k < NW; ++k) t += wsum[k];
        arr[5 * NN + 0] = t;                     // acc_top (units 2^E0)
        ((int*)(arr + 5 * NN))[2] = Etot;        // E0
      }
    }
  } else {
    // ======================= BACKWARD (adjoint, mirrored cols) =======================
    const int SPWB = 1024 / RPS;
    float2 gMa = make_float2(0.f, 0.f), gMb = make_float2(0.f, 0.f);
    float2 gYa = make_float2(0.f, 0.f), gYb = make_float2(0.f, 0.f);
    float2 accB2 = make_float2(0.f, 0.f), one2 = make_float2(1.f, 1.f);
    float2 tmx2 = make_float2(0.f, 0.f);
    float escale = 1.f, gMinC = 0.f;
    int Etot = 0;
    const float* src = tabR + c0;
    float4 pfA = *(const float4*)(src);
    float4 pfB = *(const float4*)(src + NN);
    float4 pfC = *(const float4*)(src + 2 * NN);
    float4 pfD = *(const float4*)(src + 3 * NN);
    const float* pl = src + 4 * NN;

    int cr_ = 0, pr_ = 0;
    float prevEdx = 0.f;
    auto rowB = [&](float4 ev, int k, bool first) {
      float2 e01 = make_float2(ev.x, ev.y);
      float2 e23 = make_float2(ev.z, ev.w);
      const float2 edc = E[cr_][wv][k];
      const float gMdIn = first ? gMinC : prevEdx * escale;
      const float Xi = edc.y * escale;
      prevEdx = edc.x;

      float gmh  = __shfl_up(gMb.y, 1);
      float gMd0 = isL0 ? gMdIn : gmh;
      float2 d01 = make_float2(gMd0,  gMa.x);
      float2 d23 = make_float2(gMa.y, gMb.x);
      accB2 = e01 * d01 + accB2;
      accB2 = e23 * d23 + accB2;
      float2 a01 = e01 * (d01 + one2);
      float2 a23 = e23 * (d23 + one2);

      float2 gTs01 = cGO2 * gYa + a01;
      float2 gTs23 = cGO2 * gYb + a23;
      float2 gYn01 = cGE2 * gYa + a01;
      float2 gYn23 = cGE2 * gYb + a23;

      float Qg = fmaf(cGE, fmaf(cGE, fmaf(cGE, gTs01.x, gTs01.y), gTs23.x), gTs23.y);
      float q1 = __shfl_up(Qg, 1);
      float q2 = __shfl_up(Qg, 2);
      q2 = isL1 ? Xi : q2;
      float gXin = fmaf(C4, q2, q1);
      gXin = isL0 ? Xi : gXin;
      float gX0 = fmaf(cGE, gXin, gTs01.x);
      float gX1 = fmaf(cGE, gX0,  gTs01.y);
      float gX2 = fmaf(cGE, gX1,  gTs23.x);
      float2 gMn01 = cGO2 * make_float2(gXin, gX0) + gTs01;
      float2 gMn23 = cGO2 * make_float2(gX1,  gX2) + gTs23;

      tmx2 = f2max(tmx2, f2max(gMn01, gMn23));
      tmx2 = f2max(tmx2, f2max(gYn01, gYn23));
      gMa = gMn01; gMb = gMn23; gYa = gYn01; gYb = gYn23;

      if (isL63) E[pr_][wv + 1][k] = make_float2(gMn23.y, fmaf(C4, gXin, Qg));
    };

    const int NSTEPB = SPWB + NW - 1 + 1;        // +1: epilogue row (es row 1024)
    for (int s = 0; s < NSTEPB; ++s) {
      pr_ = s & 1; cr_ = pr_ ^ 1;
      const bool actM = (s >= wv) && (s < wv + SPWB);
      const bool actE = (s == wv + SPWB);
      if (actM) {
        prevEdx = 0.f;
        for (int kk = 0; kk < RPS / 4; ++kk) {
          const int kb = kk << 2;
          float4 e0 = pfA, e1 = pfB, e2 = pfC, e3 = pfD;
          pfA = *(const float4*)pl;            pl += NN;
          pfB = *(const float4*)pl;            pl += NN;
          pfC = *(const float4*)pl;            pl += NN;
          pfD = *(const float4*)pl;            pl += NN;
          rowB(e0, kb + 0, kk == 0);
          rowB(e1, kb + 1, false);
          rowB(e2, kb + 2, false);
          rowB(e3, kb + 3, false);
        }
        gMinC = prevEdx * escale;
      } else if (actE) {
        // epilogue: accB += es[1024,.] * gM[1024,.]  (tabR row 1024 = pfA)
        float gmh  = __shfl_up(gMb.y, 1);
        float gMd0 = isL0 ? gMinC : gmh;
        float2 d01 = make_float2(gMd0,  gMa.x);
        float2 d23 = make_float2(gMa.y, gMb.x);
        accB2 = make_float2(pfA.x, pfA.y) * d01 + accB2;
        accB2 = make_float2(pfA.z, pfA.w) * d23 + accB2;
      }
      { // rescale (carries stay live to the end)
        float m = fmaxf(tmx2.x, tmx2.y);
        m = fmaxf(m, __shfl_xor(m, 1));  m = fmaxf(m, __shfl_xor(m, 2));
        m = fmaxf(m, __shfl_xor(m, 4));  m = fmaxf(m, __shfl_xor(m, 8));
        m = fmaxf(m, __shfl_xor(m, 16)); m = fmaxf(m, __shfl_xor(m, 32));
        if (lane == 0) red[pr_][wv] = m;
      }
      __syncthreads();
      {
        float mm = red[pr_][lane & (NW - 1)];
        mm = fmaxf(mm, __shfl_xor(mm, 1));
        mm = fmaxf(mm, __shfl_xor(mm, 2));
        mm = fmaxf(mm, __shfl_xor(mm, 4));
        tmx2 = make_float2(0.f, 0.f); escale = 1.f;
        int e = (mm > 0.f) ? ilogbf(mm) : 0;
        if (e > 126) e = 126; if (e < -126) e = -126;
        if (e != 0) {
          const float c = ldexpf(1.f, -e);
          const float2 c2 = make_float2(c, c);
          gMa = gMa * c2; gMb = gMb * c2;
          gYa = gYa * c2; gYb = gYb * c2;
          accB2 = accB2 * c2; one2 = one2 * c2; gMinC *= c;
          escale = c; Etot += e;
        }
      }
    }
    // write gM[1024,b], gY[1024,b]  (b = 2047-c -> reversed float4)
    *(float4*)(arr + 3 * NN + (2044 - c0)) = make_float4(gMb.y, gMb.x, gMa.y, gMa.x);
    *(float4*)(arr + 4 * NN + (2044 - c0)) = make_float4(gYb.y, gYb.x, gYa.y, gYa.x);
    float ssum = accB2.x + accB2.y;
    ssum += __shfl_xor(ssum, 1);  ssum += __shfl_xor(ssum, 2);
    ssum += __shfl_xor(ssum, 4);  ssum += __shfl_xor(ssum, 8);
    ssum += __shfl_xor(ssum, 16); ssum += __shfl_xor(ssum, 32);
    if (lane == 0) wsum[wv] = ssum;
    __syncthreads();
    if (tid == 0) {
      float t = 0.f;
      #pragma unroll
      for (int k = 0; k < NW; ++k) t += wsum[k];
      arr[5 * NN + 1] = t;                       // acc_b0 (units 2^E1)
      ((int*)(arr + 5 * NN))[3] = Etot;          // E1
    }
  }
}

// ---------------------------------------------------------------------------
// Combine (unchanged): three exponent groups
//   A0 (2^E0) = acc_top + sum_b es[1024,b+1]*S[1023,b] ;  A1 (2^E1) = acc_b0
//   A01 (2^E0+E1) = sum_b es[1024,b+1]*gM[1024,b+1]*S[1023,b]
//                 + sum_b gY[1024,b]*(cGO*T[1023,b] + cGE*Y[1023,b])
// ---------------------------------------------------------------------------
__global__ __launch_bounds__(1024)
void combine_kernel(const float* __restrict__ tab, const float* __restrict__ arr,
                    float* __restrict__ out) {
  __shared__ double sh01[16], sh0[16];
  const int tid = threadIdx.x, lane = tid & 63, wv = tid >> 6;
  const float cGE = 0.36787944117144233f;
  double t01 = 0.0, t0 = 0.0;
  for (int b = tid; b < NN; b += 1024) {
    const float S  = arr[b];
    const float tg = arr[NN + b];
    const float yc = arr[2 * NN + b];
    const float gY = arr[4 * NN + b];
    t01 += (double)gY * ((double)tg + (double)cGE * (double)yc);
    if (b < NN - 1) {
      const float es = tab[(size_t)1024 * NN + b + 1];
      const float gM = arr[3 * NN + b + 1];
      t01 += (double)es * (double)gM * (double)S;
      t0  += (double)es * (double)S;
    }
  }
  #pragma unroll
  for (int off = 1; off < 64; off <<= 1) {
    t01 += __shfl_xor(t01, off);
    t0  += __shfl_xor(t0, off);
  }
  if (lane == 0) { sh01[wv] = t01; sh0[wv] = t0; }
  __syncthreads();
  if (tid == 0) {
    double A01 = 0.0, A0 = 0.0;
    #pragma unroll
    for (int k = 0; k < 16; ++k) { A01 += sh01[k]; A0 += sh0[k]; }
    const float* resF = arr + 5 * NN;
    const float accTop = resF[0], accB = resF[1];
    const int E0 = ((const int*)resF)[2], E1 = ((const int*)resF)[3];
    A0 += (double)accTop;
    const double A1 = (double)accB;
    const long long e01 = (long long)E0 + (long long)E1;
    long long em = e01;
    if ((long long)E0 > em) em = E0;
    if ((long long)E1 > em) em = E1;
    const double tot = A01 * exp2((double)(e01 - em))
                     + A0  * exp2((double)((long long)E0 - em))
                     + A1  * exp2((double)((long long)E1 - em));
    out[0] = (float)(log(tot) + (double)em * LN2);
  }
}

extern "C" void kernel_launch(void* const* d_in, const int* in_sizes, int n_in,
                              void* d_out, int out_size, void* d_ws, size_t ws_size,
                              hipStream_t stream) {
  const float* x = (const float*)d_in[0];
  float* out = (float*)d_out;
  const size_t need = ((size_t)2 * TROWS * NN + 5 * NN + 16) * sizeof(float);
  if (ws_size >= need) {
    float* tab  = (float*)d_ws;
    float* tabR = tab + (size_t)TROWS * NN;
    float* arr  = tab + (size_t)2 * TROWS * NN;
    prep_kernel<<<dim3(NN / 256, TROWS), dim3(256), 0, stream>>>(x, tab, tabR);
    sw2_kernel<1><<<dim3(2), dim3(NW * 64), 0, stream>>>(x, tab, tabR, arr, out);
    combine_kernel<<<dim3(1), dim3(1024), 0, stream>>>(tab, arr, out);
  } else {
    sw2_kernel<0><<<dim3(1), dim3(NW * 64), 0, stream>>>(x, nullptr, nullptr, nullptr, out);
  }
}